// Round 9
// baseline (2616.712 us; speedup 1.0000x reference)
//
#include <hip/hip_runtime.h>
#include <stdint.h>

constexpr int NN = 50000;    // nodes
constexpr int NE = 500000;   // edges
constexpr int NG = 64;       // graphs
constexpr float BN_EPS = 1e-5f;

typedef __attribute__((ext_vector_type(8))) short bf16x8;
typedef __attribute__((ext_vector_type(4))) float f32x4;

// bf16 bit helpers
__device__ inline float bf2f(unsigned short u) {
    return __uint_as_float(((unsigned int)u) << 16);
}
__device__ inline float bf2f_lo(unsigned int u) {
    return __uint_as_float((u & 0xffffu) << 16);
}
__device__ inline float bf2f_hi(unsigned int u) {
    return __uint_as_float(u & 0xffff0000u);
}
__device__ inline unsigned short f2bf_rne(float f) {
    unsigned int u = __float_as_uint(f);
    unsigned int r = (u + 0x7fffu + ((u >> 16) & 1u)) >> 16;
    return (unsigned short)r;
}

// ---------- vectorized f32 row load/store ----------
template<int CPT> __device__ inline void load_row(const float* p, float* o) {
    if constexpr (CPT == 2) { float2 v = *(const float2*)p; o[0]=v.x; o[1]=v.y; }
    else if constexpr (CPT == 4) { float4 v = *(const float4*)p; o[0]=v.x; o[1]=v.y; o[2]=v.z; o[3]=v.w; }
    else { load_row<4>(p, o); load_row<4>(p+4, o+4); }
}
template<int CPT> __device__ inline void store_row(float* p, const float* v) {
    if constexpr (CPT == 2) { *(float2*)p = make_float2(v[0], v[1]); }
    else if constexpr (CPT == 4) { *(float4*)p = make_float4(v[0], v[1], v[2], v[3]); }
    else { store_row<4>(p, v); store_row<4>(p+4, v+4); }
}
template<int CPT> __device__ inline void store_hi(unsigned short* p, const float* v) {
    unsigned int w[CPT / 2];
    #pragma unroll
    for (int j = 0; j < CPT / 2; j++)
        w[j] = (unsigned int)f2bf_rne(v[2*j]) | ((unsigned int)f2bf_rne(v[2*j+1]) << 16);
    if constexpr (CPT == 2) { *(unsigned int*)p = w[0]; }
    else if constexpr (CPT == 4) { *(uint2*)p = uint2{w[0], w[1]}; }
    else { *(uint4*)p = uint4{w[0], w[1], w[2], w[3]}; }
}
// unpack 8 bf16 (uint4) -> 8 floats
__device__ inline void unpack8(uint4 u, float* f) {
    f[0]=bf2f_lo(u.x); f[1]=bf2f_hi(u.x);
    f[2]=bf2f_lo(u.y); f[3]=bf2f_hi(u.y);
    f[4]=bf2f_lo(u.z); f[5]=bf2f_hi(u.z);
    f[6]=bf2f_lo(u.w); f[7]=bf2f_hi(u.w);
}

// ---------- small utility kernels ----------
__global__ void k_zero16(uint4* p, int n) {
    int i = blockIdx.x * 256 + threadIdx.x;
    if (i < n) p[i] = uint4{0u, 0u, 0u, 0u};
}

__global__ void k_diag(float* out, int n, float val) {
    int i = blockIdx.x * 256 + threadIdx.x;
    if (i < n) out[i] = val;
}

__global__ void k_deg(const int* __restrict__ idx, int* __restrict__ cnt) {
    int e = blockIdx.x * 256 + threadIdx.x;
    if (e < NE) atomicAdd(&cnt[idx[e]], 1);
}

// single-block exclusive scan of degi[NN] -> rowptr[0..NN]
__global__ void k_scan(const int* __restrict__ degi, int* __restrict__ rowptr) {
    __shared__ int buf[1024];
    __shared__ int carry_s;
    const int tid = threadIdx.x;
    if (tid == 0) carry_s = 0;
    __syncthreads();
    for (int base = 0; base < NN; base += 1024) {
        int i = base + tid;
        int v = (i < NN) ? degi[i] : 0;
        buf[tid] = v;
        __syncthreads();
        for (int off = 1; off < 1024; off <<= 1) {
            int t = (tid >= off) ? buf[tid - off] : 0;
            __syncthreads();
            buf[tid] += t;
            __syncthreads();
        }
        if (i < NN) rowptr[i] = carry_s + buf[tid] - v;
        __syncthreads();
        if (tid == 0) carry_s += buf[1023];
        __syncthreads();
    }
    if (tid == 0) rowptr[NN] = carry_s;
}

__global__ void k_fill(const int* __restrict__ dst, const int* __restrict__ rowptr,
                       int* __restrict__ cursor, int* __restrict__ eidx) {
    int e = blockIdx.x * 256 + threadIdx.x;
    if (e < NE) {
        int d = dst[e];
        int p = atomicAdd(&cursor[d], 1);
        eidx[rowptr[d] + p] = e;
    }
}

// batch is sorted: per-graph node ranges
__global__ void k_grange(const int* __restrict__ batch, int* __restrict__ gse) {
    int n = blockIdx.x * 256 + threadIdx.x;
    if (n >= NN) return;
    int b = batch[n];
    if (n == 0 || batch[n-1] != b) gse[b] = n;
    if (n == NN-1 || batch[n+1] != b) gse[NG + b] = n + 1;
}

// ---------- BN finalize ----------
template<int OC>
__global__ void k_bnfin(const float* __restrict__ st, const float* __restrict__ g,
                        const float* __restrict__ be, float* __restrict__ dv) {
    int c = threadIdx.x;
    const float invE = 1.0f / (float)NE;
    float m = st[c] * invE;
    float v = st[OC + c] * invE - m * m;
    float sc = g[c] * rsqrtf(v + BN_EPS);
    dv[c] = sc;
    dv[OC + c] = be[c] - m * sc;
}

// ---------- pack W2 into MFMA B-fragment layout (hi/lo split bf16) ----------
// fragment (kt,nt), lane l, elem b: k = kt*32 + (l>>4)*8 + b ; n = nt*16 + (l&15)
template<int OC>
__global__ void k_packW(const float* __restrict__ W,
                        unsigned short* __restrict__ Wph, unsigned short* __restrict__ Wpl) {
    constexpr int NT = OC / 16;
    const int l = threadIdx.x;           // 64
    const int ktnt = blockIdx.x;         // KT*NT
    const int n = (ktnt % NT) * 16 + (l & 15);
    const int kbase = (ktnt / NT) * 32 + (l >> 4) * 8;
    size_t fo = ((size_t)ktnt * 64 + l) * 8;
    #pragma unroll
    for (int b = 0; b < 8; b++) {
        float w = W[(size_t)(kbase + b) * OC + n];
        unsigned short h = f2bf_rne(w);
        Wph[fo + b] = h;
        Wpl[fo + b] = f2bf_rne(w - bf2f(h));
    }
}

// ---------- node projections: A[n]=x@(W1a-W1b)+b1, B[n]=x@W1b (+ bf16-hi copies) ----------
template<int CIN, int OC>
__global__ __launch_bounds__(256) void k_nodeproj(
    const float* __restrict__ x, const float* __restrict__ W1,
    const float* __restrict__ b1, float* __restrict__ A, float* __restrict__ Bn,
    unsigned short* __restrict__ Ah, unsigned short* __restrict__ Bh)
{
    constexpr int SP = CIN + 1;
    constexpr int CPT = OC / 32;
    __shared__ float xs[32 * SP];
    const int t = threadIdx.x;
    const int n0 = blockIdx.x * 32;
    {
        const int el = t >> 3, l8 = t & 7;
        int n = n0 + el; if (n >= NN) n = NN - 1;
        const float* xp = x + (size_t)n * CIN;
        for (int k = l8; k < CIN; k += 8) xs[el * SP + k] = xp[k];
    }
    __syncthreads();
    const int tx = t & 31, ty = t >> 5;
    float accA[4][CPT], accB[4][CPT];
    #pragma unroll
    for (int i = 0; i < 4; i++)
        #pragma unroll
        for (int j = 0; j < CPT; j++) { accA[i][j] = 0.f; accB[i][j] = 0.f; }

    const float* Wa = W1 + tx * CPT;
    const float* Wb = W1 + (size_t)CIN * OC + tx * CPT;
    for (int k = 0; k < CIN; k++) {
        float wa[CPT], wb[CPT];
        load_row<CPT>(Wa + (size_t)k * OC, wa);
        load_row<CPT>(Wb + (size_t)k * OC, wb);
        #pragma unroll
        for (int i = 0; i < 4; i++) {
            float ev = xs[(ty * 4 + i) * SP + k];
            #pragma unroll
            for (int j = 0; j < CPT; j++) {
                accA[i][j] = fmaf(ev, wa[j] - wb[j], accA[i][j]);
                accB[i][j] = fmaf(ev, wb[j], accB[i][j]);
            }
        }
    }
    float bs[CPT];
    load_row<CPT>(b1 + tx * CPT, bs);
    #pragma unroll
    for (int i = 0; i < 4; i++) {
        const int n = n0 + ty * 4 + i;
        if (n < NN) {
            float va[CPT];
            #pragma unroll
            for (int j = 0; j < CPT; j++) va[j] = accA[i][j] + bs[j];
            store_row<CPT>(A  + (size_t)n * OC + tx * CPT, va);
            store_row<CPT>(Bn + (size_t)n * OC + tx * CPT, accB[i]);
            store_hi<CPT>(Ah + (size_t)n * OC + tx * CPT, va);
            store_hi<CPT>(Bh + (size_t)n * OC + tx * CPT, accB[i]);
        }
    }
}

// ---------- S[n,c] = sum over edges with dst=n of B[src_e, c] (CSR segsum) ----------
template<int OC>
__global__ __launch_bounds__(512) void k_sgather(
    const float* __restrict__ Bn,
    const int* __restrict__ src, const int* __restrict__ dst,
    const int* __restrict__ eidx, float* __restrict__ S)
{
    constexpr int ETL = 128;
    constexpr int NSEG = 512 / OC;
    constexpr int RSEG = ETL / NSEG;
    __shared__ int sdst_s[ETL], ssrc_s[ETL];
    const int t = threadIdx.x;
    const int e0 = blockIdx.x * ETL;
    const int valid = (NE - e0 < ETL) ? (NE - e0) : ETL;
    if (t < ETL) {
        int dn = -1, sn = 0;
        if (t < valid) { int e = eidx[e0 + t]; dn = dst[e]; sn = src[e]; }
        sdst_s[t] = dn; ssrc_s[t] = sn;
    }
    __syncthreads();
    const int col = t % OC;
    const int rbeg = (t / OC) * RSEG;
    float a = 0.f; int cur = -1;
    for (int r = 0; r < RSEG; r++) {
        const int gr = rbeg + r;
        if (gr >= valid) break;
        const int nd = sdst_s[gr];
        float v = Bn[(size_t)ssrc_s[gr] * OC + col];
        if (nd != cur) {
            if (cur >= 0) atomicAdd(&S[(size_t)cur * OC + col], a);
            cur = nd; a = 0.f;
        }
        a += v;
    }
    if (cur >= 0) atomicAdd(&S[(size_t)cur * OC + col], a);
}

// ---------- BN1 stats from node tables (exact factorization) ----------
// sum_c  = sum_n degIn*A + degOut*B
// sumsq_c = sum_n degIn*A^2 + degOut*B^2 + 2*A*S
template<int OC>
__global__ __launch_bounds__(256) void k_snode(
    const float* __restrict__ A, const float* __restrict__ Bn,
    const float* __restrict__ S,
    const int* __restrict__ degi, const int* __restrict__ dego,
    float* __restrict__ stats)
{
    constexpr int CPT = OC / 32;
    __shared__ float reds[4 * OC];
    __shared__ float redq[4 * OC];
    const int t = threadIdx.x;
    const int l32 = t & 31, grp = t >> 5;
    float s[CPT], q[CPT];
    #pragma unroll
    for (int j = 0; j < CPT; j++) { s[j] = 0.f; q[j] = 0.f; }
    for (int n = blockIdx.x * 8 + grp; n < NN; n += 8192) {
        const float dI = (float)degi[n], dO = (float)dego[n];
        float av[CPT], bv[CPT], sv[CPT];
        load_row<CPT>(A  + (size_t)n * OC + l32 * CPT, av);
        load_row<CPT>(Bn + (size_t)n * OC + l32 * CPT, bv);
        load_row<CPT>(S  + (size_t)n * OC + l32 * CPT, sv);
        #pragma unroll
        for (int j = 0; j < CPT; j++) {
            s[j] += dI * av[j] + dO * bv[j];
            q[j] += dI * av[j] * av[j] + dO * bv[j] * bv[j] + 2.f * av[j] * sv[j];
        }
    }
    #pragma unroll
    for (int j = 0; j < CPT; j++) {
        s[j] += __shfl_down(s[j], 32);
        q[j] += __shfl_down(q[j], 32);
    }
    const int w = t >> 6, lane = t & 63;
    if (lane < 32) {
        #pragma unroll
        for (int j = 0; j < CPT; j++) {
            reds[w * OC + lane * CPT + j] = s[j];
            redq[w * OC + lane * CPT + j] = q[j];
        }
    }
    __syncthreads();
    for (int c = t; c < OC; c += 256) {
        float S2 = reds[c] + reds[OC + c] + reds[2 * OC + c] + reds[3 * OC + c];
        float Q2 = redq[c] + redq[OC + c] + redq[2 * OC + c] + redq[3 * OC + c];
        atomicAdd(&stats[c], S2);
        atomicAdd(&stats[OC + c], Q2);
    }
}

// ---------- MFMA fused: t = relu(bn1(A[dst]+B[src])); h2 = t@W2 + b2 ----------
// 512 threads, ET=128 edges/tile, 2x4 wave grid, K chunked by 64, XOR-swizzled LDS.
// MODE 0: stats pass; gathers bf16-HI node tables (half bytes); single bf16 MFMA.
// MODE 1: exact f32 gather + 3-term hi/lo GEMM; y=relu(bn2(h2)); CSR-aggregate.
template<int OC, int MODE>
__global__ __launch_bounds__(512, 3) void k_efuse(
    const float* __restrict__ A, const float* __restrict__ Bn,
    const unsigned short* __restrict__ Ah, const unsigned short* __restrict__ Bh,
    const int* __restrict__ src, const int* __restrict__ dst,
    const int* __restrict__ eidx,
    const unsigned short* __restrict__ Wph, const unsigned short* __restrict__ Wpl,
    const float* __restrict__ b2,
    const float* __restrict__ dv1, float* __restrict__ stats,
    const float* __restrict__ dv2, float* __restrict__ xout)
{
    constexpr int ETL = 128;             // edges per tile
    constexpr int NT = OC / 16;          // n-tiles total
    constexpr int NTW = NT / 4;          // n-tiles per wave (4-way col split)
    constexpr int NCH = OC / 64;         // K chunks of 64
    constexpr int SROWS = 8192 / OC;     // rows per y-strip
    constexpr int NSTRIP = ETL / SROWS;
    constexpr int YSTR = OC + 4;
    constexpr int YB = SROWS * YSTR * 4;
    constexpr int TB = (MODE == 0) ? 16384 : 32768;   // t_hi (+t_lo for MODE1)
    constexpr int SMB = (MODE == 1 && YB > TB) ? YB : TB;
    constexpr int NSEG = 512 / OC;       // aggregation segments per strip
    constexpr int RSEG = SROWS / NSEG;   // rows per segment

    __shared__ __align__(16) unsigned char smem[SMB];
    __shared__ int sdst_s[ETL], ssrc_s[ETL];

    const int t = threadIdx.x;
    const int e0 = blockIdx.x * ETL;
    const int valid = (NE - e0 < ETL) ? (NE - e0) : ETL;

    if (t < ETL) {
        int dn = -1, sn = 0;
        if (t < valid) { int e = eidx[e0 + t]; dn = dst[e]; sn = src[e]; }
        sdst_s[t] = dn; ssrc_s[t] = sn;
    }
    __syncthreads();

    const int lane = t & 63, wave = t >> 6;
    const int rg = wave >> 2, ch = wave & 3;
    const int lr = lane & 15, lg = lane >> 4;

    f32x4 acc[4][NTW];
    #pragma unroll
    for (int m = 0; m < 4; m++)
        #pragma unroll
        for (int n = 0; n < NTW; n++) acc[m][n] = (f32x4){0.f, 0.f, 0.f, 0.f};

    const int brow = t >> 2, q = t & 3;          // 4 threads per edge-row
    const bool rvalid = (brow < valid);

    for (int kc = 0; kc < NCH; kc++) {
        // ---- build chunk kc into LDS (t_hi; +t_lo for MODE1) ----
        {
            const int gc0 = kc * 64 + q * 16;
            if (rvalid) {
                float af[16], bfv[16];
                if constexpr (MODE == 0) {
                    const unsigned short* Ar = Ah + (size_t)sdst_s[brow] * OC + gc0;
                    const unsigned short* Br = Bh + (size_t)ssrc_s[brow] * OC + gc0;
                    unpack8(*(const uint4*)(Ar), af);
                    unpack8(*(const uint4*)(Ar + 8), af + 8);
                    unpack8(*(const uint4*)(Br), bfv);
                    unpack8(*(const uint4*)(Br + 8), bfv + 8);
                } else {
                    const float* Ar = A  + (size_t)sdst_s[brow] * OC + gc0;
                    const float* Br = Bn + (size_t)ssrc_s[brow] * OC + gc0;
                    load_row<8>(Ar, af);     load_row<8>(Ar + 8, af + 8);
                    load_row<8>(Br, bfv);    load_row<8>(Br + 8, bfv + 8);
                }
                #pragma unroll
                for (int i = 0; i < 4; i++) {
                    float4 sc = *(const float4*)(dv1 + gc0 + i * 4);
                    float4 sh = *(const float4*)(dv1 + OC + gc0 + i * 4);
                    float tv[4];
                    tv[0] = fmaxf(fmaf(af[i*4+0] + bfv[i*4+0], sc.x, sh.x), 0.f);
                    tv[1] = fmaxf(fmaf(af[i*4+1] + bfv[i*4+1], sc.y, sh.y), 0.f);
                    tv[2] = fmaxf(fmaf(af[i*4+2] + bfv[i*4+2], sc.z, sh.z), 0.f);
                    tv[3] = fmaxf(fmaf(af[i*4+3] + bfv[i*4+3], sc.w, sh.w), 0.f);
                    unsigned short hv[4];
                    #pragma unroll
                    for (int j = 0; j < 4; j++) hv[j] = f2bf_rne(tv[j]);
                    const int byt = (brow * 128 + q * 32 + i * 8) ^ ((brow & 7) << 4);
                    *(ushort4*)(smem + byt) = *(ushort4*)hv;
                    if constexpr (MODE == 1) {
                        unsigned short lv[4];
                        #pragma unroll
                        for (int j = 0; j < 4; j++) lv[j] = f2bf_rne(tv[j] - bf2f(hv[j]));
                        *(ushort4*)(smem + 16384 + byt) = *(ushort4*)lv;
                    }
                }
            } else {
                const ushort4 z = ushort4{0, 0, 0, 0};
                #pragma unroll
                for (int i = 0; i < 4; i++) {
                    const int byt = (brow * 128 + q * 32 + i * 8) ^ ((brow & 7) << 4);
                    *(ushort4*)(smem + byt) = z;
                    if constexpr (MODE == 1) *(ushort4*)(smem + 16384 + byt) = z;
                }
            }
        }
        __syncthreads();

        // ---- MFMA over chunk kc ----
        #pragma unroll
        for (int kt2 = 0; kt2 < 2; kt2++) {
            bf16x8 ah[4], al[4];
            #pragma unroll
            for (int m = 0; m < 4; m++) {
                const int r = rg * 64 + m * 16 + lr;
                const int byt = (r * 128 + kt2 * 64 + lg * 16) ^ ((r & 7) << 4);
                ah[m] = *(const bf16x8*)(smem + byt);
                if constexpr (MODE == 1) al[m] = *(const bf16x8*)(smem + 16384 + byt);
            }
            #pragma unroll
            for (int n = 0; n < NTW; n++) {
                const size_t fo = ((size_t)((kc * 2 + kt2) * NT + ch * NTW + n) * 64 + lane) * 8;
                bf16x8 wh = *(const bf16x8*)(Wph + fo);
                if constexpr (MODE == 0) {
                    #pragma unroll
                    for (int m = 0; m < 4; m++)
                        acc[m][n] = __builtin_amdgcn_mfma_f32_16x16x32_bf16(ah[m], wh, acc[m][n], 0, 0, 0);
                } else {
                    bf16x8 wl = *(const bf16x8*)(Wpl + fo);
                    #pragma unroll
                    for (int m = 0; m < 4; m++) {
                        acc[m][n] = __builtin_amdgcn_mfma_f32_16x16x32_bf16(ah[m], wh, acc[m][n], 0, 0, 0);
                        acc[m][n] = __builtin_amdgcn_mfma_f32_16x16x32_bf16(ah[m], wl, acc[m][n], 0, 0, 0);
                        acc[m][n] = __builtin_amdgcn_mfma_f32_16x16x32_bf16(al[m], wh, acc[m][n], 0, 0, 0);
                    }
                }
            }
        }
        __syncthreads();
    }

    if constexpr (MODE == 0) {
        // C/D: col = lane&15, row = (lane>>4)*4 + reg (per 16x16 tile)
        #pragma unroll
        for (int n = 0; n < NTW; n++) {
            const int col = (ch * NTW + n) * 16 + lr;
            const float bb = b2[col];
            float s = 0.f, qq = 0.f;
            #pragma unroll
            for (int m = 0; m < 4; m++) {
                const int rbase = rg * 64 + m * 16 + lg * 4;
                #pragma unroll
                for (int e = 0; e < 4; e++) {
                    float h = (rbase + e < valid) ? (acc[m][n][e] + bb) : 0.f;
                    s += h; qq += h * h;
                }
            }
            s += __shfl_xor(s, 16); s += __shfl_xor(s, 32);
            qq += __shfl_xor(qq, 16); qq += __shfl_xor(qq, 32);
            if (lg == 0) {
                atomicAdd(&stats[col], s);
                atomicAdd(&stats[OC + col], qq);
            }
        }
    } else {
        // y strips in LDS -> per-column segmented sum over dst-sorted rows
        float* yt = (float*)smem;
        const int acol = t % OC;
        const int aseg = t / OC;
        #pragma unroll
        for (int s = 0; s < NSTRIP; s++) {
            const int r0 = s * SROWS;
            #pragma unroll
            for (int m = 0; m < 4; m++) {
                const int base = rg * 64 + m * 16;
                if (base >= r0 && base < r0 + SROWS) {
                    #pragma unroll
                    for (int n = 0; n < NTW; n++) {
                        const int col = (ch * NTW + n) * 16 + lr;
                        const float bb = b2[col], scv = dv2[col], shv = dv2[OC + col];
                        #pragma unroll
                        for (int e = 0; e < 4; e++) {
                            const int rl = base - r0 + lg * 4 + e;
                            yt[rl * YSTR + col] = fmaxf(fmaf(acc[m][n][e] + bb, scv, shv), 0.f);
                        }
                    }
                }
            }
            __syncthreads();
            {
                const int rbeg = aseg * RSEG;
                float a = 0.f; int cur = -1;
                for (int r = 0; r < RSEG; r++) {
                    const int gr = r0 + rbeg + r;
                    if (gr >= valid) break;
                    const int nd = sdst_s[gr];
                    if (nd != cur) {
                        if (cur >= 0) atomicAdd(&xout[(size_t)cur * OC + acol], a);
                        cur = nd; a = 0.f;
                    }
                    a += yt[(rbeg + r) * YSTR + acol];
                }
                if (cur >= 0) atomicAdd(&xout[(size_t)cur * OC + acol], a);
            }
            __syncthreads();
        }
    }
}

// ---------- divide aggregated sums by in-degree ----------
template<int OC>
__global__ __launch_bounds__(256) void k_div(float* __restrict__ xout,
                                             const int* __restrict__ degi) {
    constexpr int CPT = OC / 32;
    const int tx = threadIdx.x & 31;
    const int n = blockIdx.x * 8 + (threadIdx.x >> 5);
    if (n >= NN) return;
    const float inv = 1.0f / fmaxf((float)degi[n], 1.0f);
    float v[CPT];
    load_row<CPT>(xout + (size_t)n * OC + tx * CPT, v);
    #pragma unroll
    for (int j = 0; j < CPT; j++) v[j] *= inv;
    store_row<CPT>(xout + (size_t)n * OC + tx * CPT, v);
}

// ---------- global mean pool ----------
__global__ void k_pool(const float* __restrict__ x3, const int* __restrict__ gse,
                       float* __restrict__ pooled) {
    const int g = blockIdx.x, c = threadIdx.x;
    const int beg = gse[g], end = gse[NG + g];
    float s = 0.f;
    for (int n = beg; n < end; n++) s += x3[(size_t)n * 256 + c];
    pooled[g * 256 + c] = s / fmaxf((float)(end - beg), 1.0f);
}

// ---------- head MLP ----------
__global__ void k_head(const float* __restrict__ pooled,
                       const float* __restrict__ W1, const float* __restrict__ b1,
                       const float* __restrict__ W2, const float* __restrict__ b2,
                       float* __restrict__ out) {
    __shared__ float gv[256];
    __shared__ float z[128];
    const int g = blockIdx.x;
    gv[threadIdx.x] = pooled[g * 256 + threadIdx.x];
    __syncthreads();
    if (threadIdx.x < 128) {
        const int c = threadIdx.x;
        float s = b1[c];
        for (int k = 0; k < 256; k++) s = fmaf(gv[k], W1[k * 128 + c], s);
        z[c] = fmaxf(s, 0.f);
    }
    __syncthreads();
    if (threadIdx.x < 2) {
        const int o = threadIdx.x;
        float s = b2[o];
        for (int k = 0; k < 128; k++) s = fmaf(z[k], W2[k * 2 + o], s);
        out[g * 2 + o] = s;
    }
}

// ---------- per-block pipeline (S aliases xout: disjoint lifetimes) ----------
template<int CIN, int OC>
static void run_block(const float* xin, const float* const* Q,
                      float* A, float* B, unsigned short* Ah, unsigned short* Bh,
                      const int* src, const int* dst,
                      const int* eidx, const unsigned short* Wph, const unsigned short* Wpl,
                      float* st, float* dv, const int* degi, const int* dego,
                      float* xout, hipStream_t s)
{
    const int EG = (NE + 127) / 128;
    float* S = xout;   // S consumed by k_snode before xout is re-zeroed below
    k_nodeproj<CIN, OC><<<(NN + 31) / 32, 256, 0, s>>>(xin, Q[0], Q[1], A, B, Ah, Bh);
    // BN1 stats via factorization: S-gather (B only) + node pass
    k_zero16<<<((NN * OC / 4) + 255) / 256, 256, 0, s>>>((uint4*)S, NN * OC / 4);
    k_sgather<OC><<<EG, 512, 0, s>>>(B, src, dst, eidx, S);
    k_snode<OC><<<1024, 256, 0, s>>>(A, B, S, degi, dego, st);
    k_bnfin<OC><<<1, OC, 0, s>>>(st, Q[2], Q[3], dv);
    // BN2 stats: bf16-hi gather, single-MFMA
    k_efuse<OC, 0><<<EG, 512, 0, s>>>(A, B, Ah, Bh, src, dst, eidx, Wph, Wpl, Q[5], dv, st + 512, nullptr, nullptr);
    k_bnfin<OC><<<1, OC, 0, s>>>(st + 512, Q[6], Q[7], dv + 512);
    k_zero16<<<((NN * OC / 4) + 255) / 256, 256, 0, s>>>((uint4*)xout, NN * OC / 4);
    // exact f32 gather + 3-term GEMM + aggregate
    k_efuse<OC, 1><<<EG, 512, 0, s>>>(A, B, Ah, Bh, src, dst, eidx, Wph, Wpl, Q[5], dv, nullptr, dv + 512, xout);
    k_div<OC><<<(NN + 7) / 8, 256, 0, s>>>(xout, degi);
}

extern "C" void kernel_launch(void* const* d_in, const int* in_sizes, int n_in,
                              void* d_out, int out_size, void* d_ws, size_t ws_size,
                              hipStream_t stream)
{
    (void)in_sizes; (void)n_in;
    const float* x = (const float*)d_in[0];
    const int* ei = (const int*)d_in[1];
    const int* src = ei;
    const int* dst = ei + NE;
    const int* batch = (const int*)d_in[2];
    const float* P[28];
    for (int i = 0; i < 28; i++) P[i] = (const float*)d_in[3 + i];
    float* out = (float*)d_out;

    // workspace layout (~234 MB; ws_size is 256 MiB)
    size_t offs[21];
    {
        size_t o = 0;
        auto take = [&](size_t bytes) -> size_t {
            size_t r = o; o = (o + bytes + 255) & ~(size_t)255; return r;
        };
        offs[0] = take((size_t)NN * 256 * 4);      // A
        offs[1] = take((size_t)NN * 256 * 4);      // B
        offs[2] = take((size_t)NN * 256 * 4);      // xa  (also S for blocks 1,3)
        offs[3] = take((size_t)NN * 128 * 4);      // xb  (also S for block 2)
        offs[4] = o;                                // zero-region start
        offs[5] = take((size_t)NN * 4);             // degi (in-degree)
        offs[6] = take((size_t)NN * 4);             // dego (out-degree)
        offs[7] = take((size_t)NN * 4);             // cursor
        offs[8] = take(3 * 1024 * 4);               // stats
        offs[9] = take(2 * NG * 4);                 // gse
        offs[10] = o;                               // zero-region end
        offs[11] = take((size_t)(NN + 1) * 4);      // rowptr
        offs[12] = take((size_t)NE * 4);            // eidx
        offs[13] = take(3 * 1024 * 4);              // dv
        offs[14] = take((size_t)NG * 256 * 4);      // pooled
        offs[15] = take((64*64 + 128*128 + 256*256) * 2);   // Wpack hi
        offs[16] = take((64*64 + 128*128 + 256*256) * 2);   // Wpack lo
        offs[17] = take((size_t)NN * 256 * 2);      // Ah (bf16 hi)
        offs[18] = take((size_t)NN * 256 * 2);      // Bh (bf16 hi)
        offs[19] = o;                               // total
        if (ws_size < o) {
            float val = 1000.0f + (float)(ws_size >> 20);
            k_diag<<<(out_size + 255) / 256, 256, 0, stream>>>(out, out_size, val);
            return;
        }
    }

    char* W = (char*)d_ws;
    float* A  = (float*)(W + offs[0]);
    float* B  = (float*)(W + offs[1]);
    float* xa = (float*)(W + offs[2]);
    float* xb = (float*)(W + offs[3]);
    int* degi = (int*)(W + offs[5]);
    int* dego = (int*)(W + offs[6]);
    int* cursor = (int*)(W + offs[7]);
    float* stats = (float*)(W + offs[8]);
    int* gse = (int*)(W + offs[9]);
    int* rowptr = (int*)(W + offs[11]);
    int* eidx = (int*)(W + offs[12]);
    float* dv = (float*)(W + offs[13]);
    float* pooled = (float*)(W + offs[14]);
    unsigned short* Wph = (unsigned short*)(W + offs[15]);
    unsigned short* Wpl = (unsigned short*)(W + offs[16]);
    unsigned short* Ah = (unsigned short*)(W + offs[17]);
    unsigned short* Bh = (unsigned short*)(W + offs[18]);
    unsigned short* Wph1 = Wph,            * Wpl1 = Wpl;
    unsigned short* Wph2 = Wph + 64*64,    * Wpl2 = Wpl + 64*64;
    unsigned short* Wph3 = Wph2 + 128*128, * Wpl3 = Wpl2 + 128*128;

    // zero accumulated regions (degi, dego, cursor, stats, gse)
    int nz = (int)((offs[10] - offs[4]) / 16);
    k_zero16<<<(nz + 255) / 256, 256, 0, stream>>>((uint4*)(W + offs[4]), nz);

    // CSR by dst + degrees + per-graph ranges
    k_deg<<<(NE + 255) / 256, 256, 0, stream>>>(dst, degi);
    k_deg<<<(NE + 255) / 256, 256, 0, stream>>>(src, dego);
    k_scan<<<1, 1024, 0, stream>>>(degi, rowptr);
    k_fill<<<(NE + 255) / 256, 256, 0, stream>>>(dst, rowptr, cursor, eidx);
    k_grange<<<(NN + 255) / 256, 256, 0, stream>>>(batch, gse);

    // pack W2 of each block into MFMA fragment layout (hi/lo)
    k_packW<64> <<<(64/32)*(64/16),   64, 0, stream>>>(P[4],  Wph1, Wpl1);
    k_packW<128><<<(128/32)*(128/16), 64, 0, stream>>>(P[12], Wph2, Wpl2);
    k_packW<256><<<(256/32)*(256/16), 64, 0, stream>>>(P[20], Wph3, Wpl3);

    run_block<7,   64>(x,  P + 0,  A, B, Ah, Bh, src, dst, eidx, Wph1, Wpl1, stats + 0,    dv + 0,    degi, dego, xa, stream);
    run_block<64, 128>(xa, P + 8,  A, B, Ah, Bh, src, dst, eidx, Wph2, Wpl2, stats + 1024, dv + 1024, degi, dego, xb, stream);
    run_block<128,256>(xb, P + 16, A, B, Ah, Bh, src, dst, eidx, Wph3, Wpl3, stats + 2048, dv + 2048, degi, dego, xa, stream);

    k_pool<<<NG, 256, 0, stream>>>(xa, gse, pooled);
    k_head<<<NG, 256, 0, stream>>>(pooled, P[24], P[25], P[26], P[27], out);
}

// Round 11
// 2458.348 us; speedup vs baseline: 1.0644x; 1.0644x over previous
//
#include <hip/hip_runtime.h>
#include <stdint.h>

constexpr int NN = 50000;    // nodes
constexpr int NE = 500000;   // edges
constexpr int NG = 64;       // graphs
constexpr float BN_EPS = 1e-5f;

typedef __attribute__((ext_vector_type(8))) short bf16x8;
typedef __attribute__((ext_vector_type(4))) float f32x4;

// bf16 bit helpers
__device__ inline float bf2f(unsigned short u) {
    return __uint_as_float(((unsigned int)u) << 16);
}
__device__ inline float bf2f_lo(unsigned int u) {
    return __uint_as_float((u & 0xffffu) << 16);
}
__device__ inline float bf2f_hi(unsigned int u) {
    return __uint_as_float(u & 0xffff0000u);
}
__device__ inline unsigned short f2bf_rne(float f) {
    unsigned int u = __float_as_uint(f);
    unsigned int r = (u + 0x7fffu + ((u >> 16) & 1u)) >> 16;
    return (unsigned short)r;
}

// ---------- vectorized row load/store ----------
template<int CPT> __device__ inline void load_row(const float* p, float* o) {
    if constexpr (CPT == 2) { float2 v = *(const float2*)p; o[0]=v.x; o[1]=v.y; }
    else if constexpr (CPT == 4) { float4 v = *(const float4*)p; o[0]=v.x; o[1]=v.y; o[2]=v.z; o[3]=v.w; }
    else { load_row<4>(p, o); load_row<4>(p+4, o+4); }
}
template<int CPT> __device__ inline void store_row(float* p, const float* v) {
    if constexpr (CPT == 2) { *(float2*)p = make_float2(v[0], v[1]); }
    else if constexpr (CPT == 4) { *(float4*)p = make_float4(v[0], v[1], v[2], v[3]); }
    else { store_row<4>(p, v); store_row<4>(p+4, v+4); }
}
template<int CPT> __device__ inline void store_hi(unsigned short* p, const float* v) {
    unsigned int w[CPT / 2];
    #pragma unroll
    for (int j = 0; j < CPT / 2; j++)
        w[j] = (unsigned int)f2bf_rne(v[2*j]) | ((unsigned int)f2bf_rne(v[2*j+1]) << 16);
    if constexpr (CPT == 2) { *(unsigned int*)p = w[0]; }
    else if constexpr (CPT == 4) { *(uint2*)p = uint2{w[0], w[1]}; }
    else { *(uint4*)p = uint4{w[0], w[1], w[2], w[3]}; }
}
// unpack 8 bf16 (uint4) -> 8 floats
__device__ inline void unpack8(uint4 u, float* f) {
    f[0]=bf2f_lo(u.x); f[1]=bf2f_hi(u.x);
    f[2]=bf2f_lo(u.y); f[3]=bf2f_hi(u.y);
    f[4]=bf2f_lo(u.z); f[5]=bf2f_hi(u.z);
    f[6]=bf2f_lo(u.w); f[7]=bf2f_hi(u.w);
}
template<int CPT> __device__ inline void load_hi(const unsigned short* p, float* o) {
    if constexpr (CPT == 2) {
        unsigned int u = *(const unsigned int*)p;
        o[0]=bf2f_lo(u); o[1]=bf2f_hi(u);
    } else if constexpr (CPT == 4) {
        uint2 u = *(const uint2*)p;
        o[0]=bf2f_lo(u.x); o[1]=bf2f_hi(u.x); o[2]=bf2f_lo(u.y); o[3]=bf2f_hi(u.y);
    } else {
        unpack8(*(const uint4*)p, o);
    }
}

// ---------- small utility kernels ----------
__global__ void k_zero16(uint4* p, int n) {
    int i = blockIdx.x * 256 + threadIdx.x;
    if (i < n) p[i] = uint4{0u, 0u, 0u, 0u};
}

__global__ void k_diag(float* out, int n, float val) {
    int i = blockIdx.x * 256 + threadIdx.x;
    if (i < n) out[i] = val;
}

__global__ void k_deg(const int* __restrict__ idx, int* __restrict__ cnt) {
    int e = blockIdx.x * 256 + threadIdx.x;
    if (e < NE) atomicAdd(&cnt[idx[e]], 1);
}

// single-block exclusive scan of degi[NN] -> rowptr[0..NN]
__global__ void k_scan(const int* __restrict__ degi, int* __restrict__ rowptr) {
    __shared__ int buf[1024];
    __shared__ int carry_s;
    const int tid = threadIdx.x;
    if (tid == 0) carry_s = 0;
    __syncthreads();
    for (int base = 0; base < NN; base += 1024) {
        int i = base + tid;
        int v = (i < NN) ? degi[i] : 0;
        buf[tid] = v;
        __syncthreads();
        for (int off = 1; off < 1024; off <<= 1) {
            int t = (tid >= off) ? buf[tid - off] : 0;
            __syncthreads();
            buf[tid] += t;
            __syncthreads();
        }
        if (i < NN) rowptr[i] = carry_s + buf[tid] - v;
        __syncthreads();
        if (tid == 0) carry_s += buf[1023];
        __syncthreads();
    }
    if (tid == 0) rowptr[NN] = carry_s;
}

__global__ void k_fill(const int* __restrict__ dst, const int* __restrict__ rowptr,
                       int* __restrict__ cursor, int* __restrict__ eidx) {
    int e = blockIdx.x * 256 + threadIdx.x;
    if (e < NE) {
        int d = dst[e];
        int p = atomicAdd(&cursor[d], 1);
        eidx[rowptr[d] + p] = e;
    }
}

// batch is sorted: per-graph node ranges
__global__ void k_grange(const int* __restrict__ batch, int* __restrict__ gse) {
    int n = blockIdx.x * 256 + threadIdx.x;
    if (n >= NN) return;
    int b = batch[n];
    if (n == 0 || batch[n-1] != b) gse[b] = n;
    if (n == NN-1 || batch[n+1] != b) gse[NG + b] = n + 1;
}

// ---------- BN finalize ----------
template<int OC>
__global__ void k_bnfin(const float* __restrict__ st, const float* __restrict__ g,
                        const float* __restrict__ be, float* __restrict__ dv) {
    int c = threadIdx.x;
    const float invE = 1.0f / (float)NE;
    float m = st[c] * invE;
    float v = st[OC + c] * invE - m * m;
    float sc = g[c] * rsqrtf(v + BN_EPS);
    dv[c] = sc;
    dv[OC + c] = be[c] - m * sc;
}

// ---------- pack W2 into MFMA B-fragment layout (hi/lo split bf16) ----------
// fragment (kt,nt), lane l, elem b: k = kt*32 + (l>>4)*8 + b ; n = nt*16 + (l&15)
template<int OC>
__global__ void k_packW(const float* __restrict__ W,
                        unsigned short* __restrict__ Wph, unsigned short* __restrict__ Wpl) {
    constexpr int NT = OC / 16;
    const int l = threadIdx.x;           // 64
    const int ktnt = blockIdx.x;         // KT*NT
    const int n = (ktnt % NT) * 16 + (l & 15);
    const int kbase = (ktnt / NT) * 32 + (l >> 4) * 8;
    size_t fo = ((size_t)ktnt * 64 + l) * 8;
    #pragma unroll
    for (int b = 0; b < 8; b++) {
        float w = W[(size_t)(kbase + b) * OC + n];
        unsigned short h = f2bf_rne(w);
        Wph[fo + b] = h;
        Wpl[fo + b] = f2bf_rne(w - bf2f(h));
    }
}

// ---------- node projections: Ah[n]=bf16(x@(W1a-W1b)+b1), Bh[n]=bf16(x@W1b) ----------
// All downstream consumers (stats AND compute) use these same bf16 values, so
// BN1 stats exactly describe the data they normalize.
template<int CIN, int OC>
__global__ __launch_bounds__(256) void k_nodeproj(
    const float* __restrict__ x, const float* __restrict__ W1,
    const float* __restrict__ b1,
    unsigned short* __restrict__ Ah, unsigned short* __restrict__ Bh)
{
    constexpr int SP = CIN + 1;
    constexpr int CPT = OC / 32;
    __shared__ float xs[32 * SP];
    const int t = threadIdx.x;
    const int n0 = blockIdx.x * 32;
    {
        const int el = t >> 3, l8 = t & 7;
        int n = n0 + el; if (n >= NN) n = NN - 1;
        const float* xp = x + (size_t)n * CIN;
        for (int k = l8; k < CIN; k += 8) xs[el * SP + k] = xp[k];
    }
    __syncthreads();
    const int tx = t & 31, ty = t >> 5;
    float accA[4][CPT], accB[4][CPT];
    #pragma unroll
    for (int i = 0; i < 4; i++)
        #pragma unroll
        for (int j = 0; j < CPT; j++) { accA[i][j] = 0.f; accB[i][j] = 0.f; }

    const float* Wa = W1 + tx * CPT;
    const float* Wb = W1 + (size_t)CIN * OC + tx * CPT;
    for (int k = 0; k < CIN; k++) {
        float wa[CPT], wb[CPT];
        load_row<CPT>(Wa + (size_t)k * OC, wa);
        load_row<CPT>(Wb + (size_t)k * OC, wb);
        #pragma unroll
        for (int i = 0; i < 4; i++) {
            float ev = xs[(ty * 4 + i) * SP + k];
            #pragma unroll
            for (int j = 0; j < CPT; j++) {
                accA[i][j] = fmaf(ev, wa[j] - wb[j], accA[i][j]);
                accB[i][j] = fmaf(ev, wb[j], accB[i][j]);
            }
        }
    }
    float bs[CPT];
    load_row<CPT>(b1 + tx * CPT, bs);
    #pragma unroll
    for (int i = 0; i < 4; i++) {
        const int n = n0 + ty * 4 + i;
        if (n < NN) {
            float va[CPT];
            #pragma unroll
            for (int j = 0; j < CPT; j++) va[j] = accA[i][j] + bs[j];
            store_hi<CPT>(Ah + (size_t)n * OC + tx * CPT, va);
            store_hi<CPT>(Bh + (size_t)n * OC + tx * CPT, accB[i]);
        }
    }
}

// ---------- S[n,c] = sum over edges with dst=n of B[src_e, c] (CSR segsum, bf16 src) ----------
template<int OC>
__global__ __launch_bounds__(512) void k_sgather(
    const unsigned short* __restrict__ Bh,
    const int* __restrict__ src, const int* __restrict__ dst,
    const int* __restrict__ eidx, float* __restrict__ S)
{
    constexpr int ETL = 128;
    constexpr int HC = OC / 2;          // col-pairs per row
    constexpr int NSEG = 512 / HC;
    constexpr int RSEG = ETL / NSEG;
    __shared__ int sdst_s[ETL], ssrc_s[ETL];
    const int t = threadIdx.x;
    const int e0 = blockIdx.x * ETL;
    const int valid = (NE - e0 < ETL) ? (NE - e0) : ETL;
    if (t < ETL) {
        int dn = -1, sn = 0;
        if (t < valid) { int e = eidx[e0 + t]; dn = dst[e]; sn = src[e]; }
        sdst_s[t] = dn; ssrc_s[t] = sn;
    }
    __syncthreads();
    const int cp = (t % HC) * 2;
    const int rbeg = (t / HC) * RSEG;
    float a0 = 0.f, a1 = 0.f; int cur = -1;
    for (int r = 0; r < RSEG; r++) {
        const int gr = rbeg + r;
        if (gr >= valid) break;
        const int nd = sdst_s[gr];
        unsigned int u = *(const unsigned int*)(Bh + (size_t)ssrc_s[gr] * OC + cp);
        if (nd != cur) {
            if (cur >= 0) {
                atomicAdd(&S[(size_t)cur * OC + cp], a0);
                atomicAdd(&S[(size_t)cur * OC + cp + 1], a1);
            }
            cur = nd; a0 = 0.f; a1 = 0.f;
        }
        a0 += bf2f_lo(u); a1 += bf2f_hi(u);
    }
    if (cur >= 0) {
        atomicAdd(&S[(size_t)cur * OC + cp], a0);
        atomicAdd(&S[(size_t)cur * OC + cp + 1], a1);
    }
}

// ---------- BN1 stats from node tables (factorized; bf16 node data) ----------
// sum_c  = sum_n degIn*A + degOut*B
// sumsq_c = sum_n degIn*A^2 + degOut*B^2 + 2*A*S
template<int OC>
__global__ __launch_bounds__(256) void k_snode(
    const unsigned short* __restrict__ Ah, const unsigned short* __restrict__ Bh,
    const float* __restrict__ S,
    const int* __restrict__ degi, const int* __restrict__ dego,
    float* __restrict__ stats)
{
    constexpr int CPT = OC / 32;
    __shared__ float reds[4 * OC];
    __shared__ float redq[4 * OC];
    const int t = threadIdx.x;
    const int l32 = t & 31, grp = t >> 5;
    float s[CPT], q[CPT];
    #pragma unroll
    for (int j = 0; j < CPT; j++) { s[j] = 0.f; q[j] = 0.f; }
    for (int n = blockIdx.x * 8 + grp; n < NN; n += 8192) {
        const float dI = (float)degi[n], dO = (float)dego[n];
        float av[CPT], bv[CPT], sv[CPT];
        load_hi<CPT>(Ah + (size_t)n * OC + l32 * CPT, av);
        load_hi<CPT>(Bh + (size_t)n * OC + l32 * CPT, bv);
        load_row<CPT>(S  + (size_t)n * OC + l32 * CPT, sv);
        #pragma unroll
        for (int j = 0; j < CPT; j++) {
            s[j] += dI * av[j] + dO * bv[j];
            q[j] += dI * av[j] * av[j] + dO * bv[j] * bv[j] + 2.f * av[j] * sv[j];
        }
    }
    #pragma unroll
    for (int j = 0; j < CPT; j++) {
        s[j] += __shfl_down(s[j], 32);
        q[j] += __shfl_down(q[j], 32);
    }
    const int w = t >> 6, lane = t & 63;
    if (lane < 32) {
        #pragma unroll
        for (int j = 0; j < CPT; j++) {
            reds[w * OC + lane * CPT + j] = s[j];
            redq[w * OC + lane * CPT + j] = q[j];
        }
    }
    __syncthreads();
    for (int c = t; c < OC; c += 256) {
        float S2 = reds[c] + reds[OC + c] + reds[2 * OC + c] + reds[3 * OC + c];
        float Q2 = redq[c] + redq[OC + c] + redq[2 * OC + c] + redq[3 * OC + c];
        atomicAdd(&stats[c], S2);
        atomicAdd(&stats[OC + c], Q2);
    }
}

// ---------- MFMA fused: t = relu(bn1(Ah[dst]+Bh[src])); h2 = t@W2 + b2 ----------
// 512 threads, ET=128 edges/tile, 2x4 wave grid, K chunked by 64, XOR-swizzled LDS.
// Both modes gather bf16 node tables (half bytes+requests vs f32).
// MODE 0: stats pass; single bf16 MFMA (stat-level precision).
// MODE 1: 3-term hi/lo GEMM on f32 t (bn1 output); y=relu(bn2(h2)); CSR-aggregate.
template<int OC, int MODE>
__global__ __launch_bounds__(512, 3) void k_efuse(
    const unsigned short* __restrict__ Ah, const unsigned short* __restrict__ Bh,
    const int* __restrict__ src, const int* __restrict__ dst,
    const int* __restrict__ eidx,
    const unsigned short* __restrict__ Wph, const unsigned short* __restrict__ Wpl,
    const float* __restrict__ b2,
    const float* __restrict__ dv1, float* __restrict__ stats,
    const float* __restrict__ dv2, float* __restrict__ xout)
{
    constexpr int ETL = 128;             // edges per tile
    constexpr int NT = OC / 16;          // n-tiles total
    constexpr int NTW = NT / 4;          // n-tiles per wave (4-way col split)
    constexpr int NCH = OC / 64;         // K chunks of 64
    constexpr int SROWS = 8192 / OC;     // rows per y-strip
    constexpr int NSTRIP = ETL / SROWS;
    constexpr int YSTR = OC + 4;
    constexpr int YB = SROWS * YSTR * 4;
    constexpr int TB = (MODE == 0) ? 16384 : 32768;   // t_hi (+t_lo for MODE1)
    constexpr int SMB = (MODE == 1 && YB > TB) ? YB : TB;
    constexpr int NSEG = 512 / OC;       // aggregation segments per strip
    constexpr int RSEG = SROWS / NSEG;   // rows per segment

    __shared__ __align__(16) unsigned char smem[SMB];
    __shared__ int sdst_s[ETL], ssrc_s[ETL];

    const int t = threadIdx.x;
    const int e0 = blockIdx.x * ETL;
    const int valid = (NE - e0 < ETL) ? (NE - e0) : ETL;

    if (t < ETL) {
        int dn = -1, sn = 0;
        if (t < valid) { int e = eidx[e0 + t]; dn = dst[e]; sn = src[e]; }
        sdst_s[t] = dn; ssrc_s[t] = sn;
    }
    __syncthreads();

    const int lane = t & 63, wave = t >> 6;
    const int rg = wave >> 2, ch = wave & 3;
    const int lr = lane & 15, lg = lane >> 4;

    f32x4 acc[4][NTW];
    #pragma unroll
    for (int m = 0; m < 4; m++)
        #pragma unroll
        for (int n = 0; n < NTW; n++) acc[m][n] = (f32x4){0.f, 0.f, 0.f, 0.f};

    const int brow = t >> 2, q = t & 3;          // 4 threads per edge-row
    const bool rvalid = (brow < valid);

    for (int kc = 0; kc < NCH; kc++) {
        // ---- build chunk kc into LDS (t_hi; +t_lo for MODE1), bf16 gathers ----
        {
            const int gc0 = kc * 64 + q * 16;
            if (rvalid) {
                float af[16], bfv[16];
                const unsigned short* Ar = Ah + (size_t)sdst_s[brow] * OC + gc0;
                const unsigned short* Br = Bh + (size_t)ssrc_s[brow] * OC + gc0;
                unpack8(*(const uint4*)(Ar), af);
                unpack8(*(const uint4*)(Ar + 8), af + 8);
                unpack8(*(const uint4*)(Br), bfv);
                unpack8(*(const uint4*)(Br + 8), bfv + 8);
                #pragma unroll
                for (int i = 0; i < 4; i++) {
                    float4 sc = *(const float4*)(dv1 + gc0 + i * 4);
                    float4 sh = *(const float4*)(dv1 + OC + gc0 + i * 4);
                    float tv[4];
                    tv[0] = fmaxf(fmaf(af[i*4+0] + bfv[i*4+0], sc.x, sh.x), 0.f);
                    tv[1] = fmaxf(fmaf(af[i*4+1] + bfv[i*4+1], sc.y, sh.y), 0.f);
                    tv[2] = fmaxf(fmaf(af[i*4+2] + bfv[i*4+2], sc.z, sh.z), 0.f);
                    tv[3] = fmaxf(fmaf(af[i*4+3] + bfv[i*4+3], sc.w, sh.w), 0.f);
                    unsigned short hv[4];
                    #pragma unroll
                    for (int j = 0; j < 4; j++) hv[j] = f2bf_rne(tv[j]);
                    const int byt = (brow * 128 + q * 32 + i * 8) ^ ((brow & 7) << 4);
                    *(ushort4*)(smem + byt) = *(ushort4*)hv;
                    if constexpr (MODE == 1) {
                        unsigned short lv[4];
                        #pragma unroll
                        for (int j = 0; j < 4; j++) lv[j] = f2bf_rne(tv[j] - bf2f(hv[j]));
                        *(ushort4*)(smem + 16384 + byt) = *(ushort4*)lv;
                    }
                }
            } else {
                const ushort4 z = ushort4{0, 0, 0, 0};
                #pragma unroll
                for (int i = 0; i < 4; i++) {
                    const int byt = (brow * 128 + q * 32 + i * 8) ^ ((brow & 7) << 4);
                    *(ushort4*)(smem + byt) = z;
                    if constexpr (MODE == 1) *(ushort4*)(smem + 16384 + byt) = z;
                }
            }
        }
        __syncthreads();

        // ---- MFMA over chunk kc ----
        #pragma unroll
        for (int kt2 = 0; kt2 < 2; kt2++) {
            bf16x8 ah[4], al[4];
            #pragma unroll
            for (int m = 0; m < 4; m++) {
                const int r = rg * 64 + m * 16 + lr;
                const int byt = (r * 128 + kt2 * 64 + lg * 16) ^ ((r & 7) << 4);
                ah[m] = *(const bf16x8*)(smem + byt);
                if constexpr (MODE == 1) al[m] = *(const bf16x8*)(smem + 16384 + byt);
            }
            #pragma unroll
            for (int n = 0; n < NTW; n++) {
                const size_t fo = ((size_t)((kc * 2 + kt2) * NT + ch * NTW + n) * 64 + lane) * 8;
                bf16x8 wh = *(const bf16x8*)(Wph + fo);
                if constexpr (MODE == 0) {
                    #pragma unroll
                    for (int m = 0; m < 4; m++)
                        acc[m][n] = __builtin_amdgcn_mfma_f32_16x16x32_bf16(ah[m], wh, acc[m][n], 0, 0, 0);
                } else {
                    bf16x8 wl = *(const bf16x8*)(Wpl + fo);
                    #pragma unroll
                    for (int m = 0; m < 4; m++) {
                        acc[m][n] = __builtin_amdgcn_mfma_f32_16x16x32_bf16(ah[m], wh, acc[m][n], 0, 0, 0);
                        acc[m][n] = __builtin_amdgcn_mfma_f32_16x16x32_bf16(ah[m], wl, acc[m][n], 0, 0, 0);
                        acc[m][n] = __builtin_amdgcn_mfma_f32_16x16x32_bf16(al[m], wh, acc[m][n], 0, 0, 0);
                    }
                }
            }
        }
        __syncthreads();
    }

    if constexpr (MODE == 0) {
        // C/D: col = lane&15, row = (lane>>4)*4 + reg (per 16x16 tile)
        #pragma unroll
        for (int n = 0; n < NTW; n++) {
            const int col = (ch * NTW + n) * 16 + lr;
            const float bb = b2[col];
            float s = 0.f, qq = 0.f;
            #pragma unroll
            for (int m = 0; m < 4; m++) {
                const int rbase = rg * 64 + m * 16 + lg * 4;
                #pragma unroll
                for (int e = 0; e < 4; e++) {
                    float h = (rbase + e < valid) ? (acc[m][n][e] + bb) : 0.f;
                    s += h; qq += h * h;
                }
            }
            s += __shfl_xor(s, 16); s += __shfl_xor(s, 32);
            qq += __shfl_xor(qq, 16); qq += __shfl_xor(qq, 32);
            if (lg == 0) {
                atomicAdd(&stats[col], s);
                atomicAdd(&stats[OC + col], qq);
            }
        }
    } else {
        // y strips in LDS -> per-column segmented sum over dst-sorted rows
        float* yt = (float*)smem;
        const int acol = t % OC;
        const int aseg = t / OC;
        #pragma unroll
        for (int s = 0; s < NSTRIP; s++) {
            const int r0 = s * SROWS;
            #pragma unroll
            for (int m = 0; m < 4; m++) {
                const int base = rg * 64 + m * 16;
                if (base >= r0 && base < r0 + SROWS) {
                    #pragma unroll
                    for (int n = 0; n < NTW; n++) {
                        const int col = (ch * NTW + n) * 16 + lr;
                        const float bb = b2[col], scv = dv2[col], shv = dv2[OC + col];
                        #pragma unroll
                        for (int e = 0; e < 4; e++) {
                            const int rl = base - r0 + lg * 4 + e;
                            yt[rl * YSTR + col] = fmaxf(fmaf(acc[m][n][e] + bb, scv, shv), 0.f);
                        }
                    }
                }
            }
            __syncthreads();
            {
                const int rbeg = aseg * RSEG;
                float a = 0.f; int cur = -1;
                for (int r = 0; r < RSEG; r++) {
                    const int gr = r0 + rbeg + r;
                    if (gr >= valid) break;
                    const int nd = sdst_s[gr];
                    if (nd != cur) {
                        if (cur >= 0) atomicAdd(&xout[(size_t)cur * OC + acol], a);
                        cur = nd; a = 0.f;
                    }
                    a += yt[(rbeg + r) * YSTR + acol];
                }
                if (cur >= 0) atomicAdd(&xout[(size_t)cur * OC + acol], a);
            }
            __syncthreads();
        }
    }
}

// ---------- divide aggregated sums by in-degree ----------
template<int OC>
__global__ __launch_bounds__(256) void k_div(float* __restrict__ xout,
                                             const int* __restrict__ degi) {
    constexpr int CPT = OC / 32;
    const int tx = threadIdx.x & 31;
    const int n = blockIdx.x * 8 + (threadIdx.x >> 5);
    if (n >= NN) return;
    const float inv = 1.0f / fmaxf((float)degi[n], 1.0f);
    float v[CPT];
    load_row<CPT>(xout + (size_t)n * OC + tx * CPT, v);
    #pragma unroll
    for (int j = 0; j < CPT; j++) v[j] *= inv;
    store_row<CPT>(xout + (size_t)n * OC + tx * CPT, v);
}

// ---------- global mean pool ----------
__global__ void k_pool(const float* __restrict__ x3, const int* __restrict__ gse,
                       float* __restrict__ pooled) {
    const int g = blockIdx.x, c = threadIdx.x;
    const int beg = gse[g], end = gse[NG + g];
    float s = 0.f;
    for (int n = beg; n < end; n++) s += x3[(size_t)n * 256 + c];
    pooled[g * 256 + c] = s / fmaxf((float)(end - beg), 1.0f);
}

// ---------- head MLP ----------
__global__ void k_head(const float* __restrict__ pooled,
                       const float* __restrict__ W1, const float* __restrict__ b1,
                       const float* __restrict__ W2, const float* __restrict__ b2,
                       float* __restrict__ out) {
    __shared__ float gv[256];
    __shared__ float z[128];
    const int g = blockIdx.x;
    gv[threadIdx.x] = pooled[g * 256 + threadIdx.x];
    __syncthreads();
    if (threadIdx.x < 128) {
        const int c = threadIdx.x;
        float s = b1[c];
        for (int k = 0; k < 256; k++) s = fmaf(gv[k], W1[k * 128 + c], s);
        z[c] = fmaxf(s, 0.f);
    }
    __syncthreads();
    if (threadIdx.x < 2) {
        const int o = threadIdx.x;
        float s = b2[o];
        for (int k = 0; k < 128; k++) s = fmaf(z[k], W2[k * 2 + o], s);
        out[g * 2 + o] = s;
    }
}

// ---------- per-block pipeline (S aliases xout: disjoint lifetimes) ----------
template<int CIN, int OC>
static void run_block(const float* xin, const float* const* Q,
                      unsigned short* Ah, unsigned short* Bh,
                      const int* src, const int* dst,
                      const int* eidx, const unsigned short* Wph, const unsigned short* Wpl,
                      float* st, float* dv, const int* degi, const int* dego,
                      float* xout, hipStream_t s)
{
    const int EG = (NE + 127) / 128;
    float* S = xout;   // S consumed by k_snode before xout is re-zeroed below
    k_nodeproj<CIN, OC><<<(NN + 31) / 32, 256, 0, s>>>(xin, Q[0], Q[1], Ah, Bh);
    // BN1 stats via factorization: S-gather (bf16 B) + node pass
    k_zero16<<<((NN * OC / 4) + 255) / 256, 256, 0, s>>>((uint4*)S, NN * OC / 4);
    k_sgather<OC><<<EG, 512, 0, s>>>(Bh, src, dst, eidx, S);
    k_snode<OC><<<1024, 256, 0, s>>>(Ah, Bh, S, degi, dego, st);
    k_bnfin<OC><<<1, OC, 0, s>>>(st, Q[2], Q[3], dv);
    // BN2 stats: bf16 gather, single-MFMA
    k_efuse<OC, 0><<<EG, 512, 0, s>>>(Ah, Bh, src, dst, eidx, Wph, Wpl, Q[5], dv, st + 512, nullptr, nullptr);
    k_bnfin<OC><<<1, OC, 0, s>>>(st + 512, Q[6], Q[7], dv + 512);
    k_zero16<<<((NN * OC / 4) + 255) / 256, 256, 0, s>>>((uint4*)xout, NN * OC / 4);
    // bf16 gather + 3-term GEMM + aggregate
    k_efuse<OC, 1><<<EG, 512, 0, s>>>(Ah, Bh, src, dst, eidx, Wph, Wpl, Q[5], dv, nullptr, dv + 512, xout);
    k_div<OC><<<(NN + 7) / 8, 256, 0, s>>>(xout, degi);
}

extern "C" void kernel_launch(void* const* d_in, const int* in_sizes, int n_in,
                              void* d_out, int out_size, void* d_ws, size_t ws_size,
                              hipStream_t stream)
{
    (void)in_sizes; (void)n_in;
    const float* x = (const float*)d_in[0];
    const int* ei = (const int*)d_in[1];
    const int* src = ei;
    const int* dst = ei + NE;
    const int* batch = (const int*)d_in[2];
    const float* P[28];
    for (int i = 0; i < 28; i++) P[i] = (const float*)d_in[3 + i];
    float* out = (float*)d_out;

    // workspace layout (~158 MB; ws_size is 256 MiB)
    size_t offs[19];
    {
        size_t o = 0;
        auto take = [&](size_t bytes) -> size_t {
            size_t r = o; o = (o + bytes + 255) & ~(size_t)255; return r;
        };
        offs[0] = take((size_t)NN * 256 * 2);      // Ah (bf16)
        offs[1] = take((size_t)NN * 256 * 2);      // Bh (bf16)
        offs[2] = take((size_t)NN * 256 * 4);      // xa  (also S for blocks 1,3)
        offs[3] = take((size_t)NN * 128 * 4);      // xb  (also S for block 2)
        offs[4] = o;                                // zero-region start
        offs[5] = take((size_t)NN * 4);             // degi (in-degree)
        offs[6] = take((size_t)NN * 4);             // dego (out-degree)
        offs[7] = take((size_t)NN * 4);             // cursor
        offs[8] = take(3 * 1024 * 4);               // stats
        offs[9] = take(2 * NG * 4);                 // gse
        offs[10] = o;                               // zero-region end
        offs[11] = take((size_t)(NN + 1) * 4);      // rowptr
        offs[12] = take((size_t)NE * 4);            // eidx
        offs[13] = take(3 * 1024 * 4);              // dv
        offs[14] = take((size_t)NG * 256 * 4);      // pooled
        offs[15] = take((64*64 + 128*128 + 256*256) * 2);   // Wpack hi
        offs[16] = take((64*64 + 128*128 + 256*256) * 2);   // Wpack lo
        offs[17] = o;                               // total
        if (ws_size < o) {
            float val = 1000.0f + (float)(ws_size >> 20);
            k_diag<<<(out_size + 255) / 256, 256, 0, stream>>>(out, out_size, val);
            return;
        }
    }

    char* W = (char*)d_ws;
    unsigned short* Ah = (unsigned short*)(W + offs[0]);
    unsigned short* Bh = (unsigned short*)(W + offs[1]);
    float* xa = (float*)(W + offs[2]);
    float* xb = (float*)(W + offs[3]);
    int* degi = (int*)(W + offs[5]);
    int* dego = (int*)(W + offs[6]);
    int* cursor = (int*)(W + offs[7]);
    float* stats = (float*)(W + offs[8]);
    int* gse = (int*)(W + offs[9]);
    int* rowptr = (int*)(W + offs[11]);
    int* eidx = (int*)(W + offs[12]);
    float* dv = (float*)(W + offs[13]);
    float* pooled = (float*)(W + offs[14]);
    unsigned short* Wph = (unsigned short*)(W + offs[15]);
    unsigned short* Wpl = (unsigned short*)(W + offs[16]);
    unsigned short* Wph1 = Wph,            * Wpl1 = Wpl;
    unsigned short* Wph2 = Wph + 64*64,    * Wpl2 = Wpl + 64*64;
    unsigned short* Wph3 = Wph2 + 128*128, * Wpl3 = Wpl2 + 128*128;

    // zero accumulated regions (degi, dego, cursor, stats, gse)
    int nz = (int)((offs[10] - offs[4]) / 16);
    k_zero16<<<(nz + 255) / 256, 256, 0, stream>>>((uint4*)(W + offs[4]), nz);

    // CSR by dst + degrees + per-graph ranges
    k_deg<<<(NE + 255) / 256, 256, 0, stream>>>(dst, degi);
    k_deg<<<(NE + 255) / 256, 256, 0, stream>>>(src, dego);
    k_scan<<<1, 1024, 0, stream>>>(degi, rowptr);
    k_fill<<<(NE + 255) / 256, 256, 0, stream>>>(dst, rowptr, cursor, eidx);
    k_grange<<<(NN + 255) / 256, 256, 0, stream>>>(batch, gse);

    // pack W2 of each block into MFMA fragment layout (hi/lo)
    k_packW<64> <<<(64/32)*(64/16),   64, 0, stream>>>(P[4],  Wph1, Wpl1);
    k_packW<128><<<(128/32)*(128/16), 64, 0, stream>>>(P[12], Wph2, Wpl2);
    k_packW<256><<<(256/32)*(256/16), 64, 0, stream>>>(P[20], Wph3, Wpl3);

    run_block<7,   64>(x,  P + 0,  Ah, Bh, src, dst, eidx, Wph1, Wpl1, stats + 0,    dv + 0,    degi, dego, xa, stream);
    run_block<64, 128>(xa, P + 8,  Ah, Bh, src, dst, eidx, Wph2, Wpl2, stats + 1024, dv + 1024, degi, dego, xb, stream);
    run_block<128,256>(xb, P + 16, Ah, Bh, src, dst, eidx, Wph3, Wpl3, stats + 2048, dv + 2048, degi, dego, xa, stream);

    k_pool<<<NG, 256, 0, stream>>>(xa, gse, pooled);
    k_head<<<NG, 256, 0, stream>>>(pooled, P[24], P[25], P[26], P[27], out);
}